// Round 1
// baseline (271.161 us; speedup 1.0000x reference)
//
#include <hip/hip_runtime.h>

#define CHANNELS 3
#define HW 512
#define KS 15
#define GPAD 7
#define TILE 64
#define HT (TILE + 2 * GPAD)   // 78 (tile + halo)
#define IN_STR 81              // odd stride: 2-way max bank aliasing on column walks
#define MID_STR 65             // r*65 % 32 = (r + 2r*32...) -> consecutive rows hit consecutive banks

__global__ __launch_bounds__(256)
void gauss_blur_kernel(const float* __restrict__ x,
                       const float* __restrict__ sigma,
                       float* __restrict__ out) {
    __shared__ float in_s[HT * IN_STR];    // 78 x 81 floats = 25272 B
    __shared__ float mid_s[HT * MID_STR];  // 78 x 65 floats = 20280 B

    const int tid   = threadIdx.x;   // 0..255
    const int tileX = blockIdx.x;    // 0..7
    const int tileY = blockIdx.y;    // 0..7
    const int bc    = blockIdx.z;    // 0..B*C-1
    const int b     = bc / CHANNELS;

    // ---- per-batch 1D Gaussian weights (separable; normalization by S matches
    // reference's S^2+1e-8 to within 1e-8 relative since S >= 1) ----
    float w[KS];
    {
        const float s = sigma[b];
        const float inv_denom = 1.0f / (2.0f * s * s + 1e-8f);
        float sum = 0.0f;
        #pragma unroll
        for (int i = 0; i < KS; ++i) {
            const float d = (float)(i - GPAD);
            const float g = __expf(-d * d * inv_denom);
            w[i] = g;
            sum += g;
        }
        const float inv = 1.0f / sum;
        #pragma unroll
        for (int i = 0; i < KS; ++i) w[i] *= inv;
    }

    const size_t plane = (size_t)HW * HW;
    const float* xp = x + (size_t)bc * plane;
    float* op       = out + (size_t)bc * plane;
    const int gx0 = tileX * TILE - GPAD;
    const int gy0 = tileY * TILE - GPAD;

    // ---- stage 1: global -> LDS, 78x78 tile with zero padding ----
    for (int i = tid; i < HT * HT; i += 256) {
        const int r = i / HT;
        const int c = i - r * HT;
        const int gy = gy0 + r;
        const int gx = gx0 + c;
        float v = 0.0f;
        if ((unsigned)gy < (unsigned)HW && (unsigned)gx < (unsigned)HW)
            v = xp[gy * HW + gx];
        in_s[r * IN_STR + c] = v;
    }
    __syncthreads();

    // ---- stage 2: horizontal pass. mid[r][c] = sum_k w[k]*in[r][c+k]
    // 78 rows x 4 chunks of 16 outputs; register sliding window (30 LDS reads
    // per 16 outputs instead of 15 per output). Row-major lane mapping keeps
    // LDS reads at worst 2-way (stride 81). ----
    for (int t = tid; t < HT * 4; t += 256) {
        const int r  = t % HT;
        const int cc = (t / HT) * 16;
        const float* src = &in_s[r * IN_STR + cc];
        float buf[16 + KS - 1];
        #pragma unroll
        for (int j = 0; j < 16 + KS - 1; ++j) buf[j] = src[j];
        float* dst = &mid_s[r * MID_STR + cc];
        #pragma unroll
        for (int o = 0; o < 16; ++o) {
            float acc = 0.0f;
            #pragma unroll
            for (int k = 0; k < KS; ++k) acc = fmaf(w[k], buf[o + k], acc);
            dst[o] = acc;
        }
    }
    __syncthreads();

    // ---- stage 3: vertical pass. Each thread: one column, 16 consecutive
    // output rows. 30 LDS reads -> 16 outputs. Lanes walk consecutive columns
    // -> coalesced global stores, <=2-way LDS aliasing. ----
    {
        const int c  = tid & (TILE - 1);
        const int r0 = (tid >> 6) * 16;
        float buf[16 + KS - 1];
        #pragma unroll
        for (int j = 0; j < 16 + KS - 1; ++j)
            buf[j] = mid_s[(r0 + j) * MID_STR + c];
        const int gx = tileX * TILE + c;
        #pragma unroll
        for (int o = 0; o < 16; ++o) {
            float acc = 0.0f;
            #pragma unroll
            for (int k = 0; k < KS; ++k) acc = fmaf(w[k], buf[o + k], acc);
            op[(size_t)(tileY * TILE + r0 + o) * HW + gx] = acc;
        }
    }
}

extern "C" void kernel_launch(void* const* d_in, const int* in_sizes, int n_in,
                              void* d_out, int out_size, void* d_ws, size_t ws_size,
                              hipStream_t stream) {
    const float* x     = (const float*)d_in[0];
    const float* sigma = (const float*)d_in[1];
    float* out         = (float*)d_out;
    const int B = in_sizes[1];  // 32
    dim3 grid(HW / TILE, HW / TILE, B * CHANNELS);
    gauss_blur_kernel<<<grid, dim3(256, 1, 1), 0, stream>>>(x, sigma, out);
}

// Round 2
// 237.497 us; speedup vs baseline: 1.1417x; 1.1417x over previous
//
#include <hip/hip_runtime.h>

#define CHANNELS 3
#define HW 512
#define KS 15
#define GPAD 7
#define TILE 64
#define HT (TILE + 2 * GPAD)   // 78 mid rows
#define MID_STR (TILE + 1)     // 65: consecutive rows -> consecutive banks; col walks free
#define WIN (16 + KS - 1)      // 30-tap window per 16-output chunk

// Accumulate one input element (window index J) into the 16 sliding-window outputs.
template<int J>
__device__ __forceinline__ void acc_tap(float (&acc)[16], const float (&w)[KS], float v) {
    if constexpr (J >= 0 && J < WIN) {
        constexpr int lo = (J - (KS - 1)) > 0 ? (J - (KS - 1)) : 0;
        constexpr int hi = (J < 15) ? J : 15;
        #pragma unroll
        for (int o = lo; o <= hi; ++o) acc[o] = fmaf(w[J - o], v, acc[o]);
    }
}

// One float4 of the aligned 32-float window; element m = 4Q+e maps to J = m-1
// (the aligned window starts one float before the first needed input).
template<int Q>
__device__ __forceinline__ void acc_quad(float (&acc)[16], const float (&w)[KS], float4 v) {
    acc_tap<4 * Q - 1>(acc, w, v.x);
    acc_tap<4 * Q + 0>(acc, w, v.y);
    acc_tap<4 * Q + 1>(acc, w, v.z);
    acc_tap<4 * Q + 2>(acc, w, v.w);
}

__global__ __launch_bounds__(256, 7)   // 7 blocks/CU (VGPR cap 72); LDS alone allows 8
void gauss_blur_kernel(const float* __restrict__ x,
                       const float* __restrict__ sigma,
                       float* __restrict__ out) {
    __shared__ float mid_s[HT * MID_STR];  // 78 x 65 floats = 20280 B -> 8 blocks/CU by LDS

    const int tid   = threadIdx.x;   // 0..255
    const int tileX = blockIdx.x;    // 0..7
    const int tileY = blockIdx.y;    // 0..7
    const int bc    = blockIdx.z;    // 0..B*C-1
    const int b     = bc / CHANNELS;

    // per-batch 1D Gaussian weights (separable; S^2+1e-8 vs (S1)^2 diff <= 1e-8 rel)
    float w[KS];
    {
        const float s = sigma[b];
        const float inv_denom = 1.0f / (2.0f * s * s + 1e-8f);
        float sum = 0.0f;
        #pragma unroll
        for (int i = 0; i < KS; ++i) {
            const float d = (float)(i - GPAD);
            const float g = __expf(-d * d * inv_denom);
            w[i] = g;
            sum += g;
        }
        const float inv = 1.0f / sum;
        #pragma unroll
        for (int i = 0; i < KS; ++i) w[i] *= inv;
    }

    const size_t plane = (size_t)HW * HW;
    const float* xp = x + (size_t)bc * plane;
    float* op       = out + (size_t)bc * plane;
    const int gy0 = tileY * TILE - GPAD;

    // ---- stage A: horizontal pass, straight from global (no input staging).
    // 78 rows x 4 chunks of 16 outputs. Lane i -> (row i>>2, chunk i&3); a wave
    // covers 16 consecutive rows, so the 8 float4 loads/lane hit L1-resident
    // lines after first touch. Aligned window: floats [cc0-8, cc0+24). ----
    for (int i = tid; i < HT * 4; i += 256) {
        const int r  = i >> 2;
        const int ch = i & 3;
        float acc[16];
        #pragma unroll
        for (int o = 0; o < 16; ++o) acc[o] = 0.0f;

        const int gy = gy0 + r;
        if ((unsigned)gy < (unsigned)HW) {
            const float* rowp = xp + (size_t)gy * HW;
            const int cc0 = tileX * TILE + ch * 16;  // global col of this chunk's output 0
            const int a0  = cc0 - 8;                 // 16B-aligned window start
            if (a0 >= 0 && a0 + 32 <= HW) {
                const float4* v4 = (const float4*)(rowp + a0);
                acc_quad<0>(acc, w, v4[0]);
                acc_quad<1>(acc, w, v4[1]);
                acc_quad<2>(acc, w, v4[2]);
                acc_quad<3>(acc, w, v4[3]);
                acc_quad<4>(acc, w, v4[4]);
                acc_quad<5>(acc, w, v4[5]);
                acc_quad<6>(acc, w, v4[6]);
                acc_quad<7>(acc, w, v4[7]);
            } else {
                // image edge: scalar loads with per-column zero padding
                #pragma unroll
                for (int j = 0; j < WIN; ++j) {
                    const int col = cc0 - GPAD + j;
                    float v = 0.0f;
                    if ((unsigned)col < (unsigned)HW) v = rowp[col];
                    const int lo = (j - (KS - 1)) > 0 ? (j - (KS - 1)) : 0;
                    const int hi = (j < 15) ? j : 15;
                    #pragma unroll
                    for (int o = lo; o <= hi; ++o) acc[o] = fmaf(w[j - o], v, acc[o]);
                }
            }
        }
        float* dst = &mid_s[r * MID_STR + ch * 16];
        #pragma unroll
        for (int o = 0; o < 16; ++o) dst[o] = acc[o];  // <=2-way bank aliasing: free
    }
    __syncthreads();

    // ---- stage B: vertical pass from LDS. Thread -> (col tid&63, 16 rows).
    // 30 scalar LDS reads per 16 outputs; lanes walk consecutive cols ->
    // conflict-free reads and coalesced 256B global stores. ----
    {
        const int c  = tid & (TILE - 1);
        const int r0 = (tid >> 6) * 16;
        float acc[16];
        #pragma unroll
        for (int o = 0; o < 16; ++o) acc[o] = 0.0f;
        #pragma unroll
        for (int j = 0; j < WIN; ++j) {
            const float v = mid_s[(r0 + j) * MID_STR + c];
            const int lo = (j - (KS - 1)) > 0 ? (j - (KS - 1)) : 0;
            const int hi = (j < 15) ? j : 15;
            #pragma unroll
            for (int o = lo; o <= hi; ++o) acc[o] = fmaf(w[j - o], v, acc[o]);
        }
        const int gx = tileX * TILE + c;
        #pragma unroll
        for (int o = 0; o < 16; ++o)
            op[(size_t)(tileY * TILE + r0 + o) * HW + gx] = acc[o];
    }
}

extern "C" void kernel_launch(void* const* d_in, const int* in_sizes, int n_in,
                              void* d_out, int out_size, void* d_ws, size_t ws_size,
                              hipStream_t stream) {
    const float* x     = (const float*)d_in[0];
    const float* sigma = (const float*)d_in[1];
    float* out         = (float*)d_out;
    const int B = in_sizes[1];  // 32
    dim3 grid(HW / TILE, HW / TILE, B * CHANNELS);
    gauss_blur_kernel<<<grid, dim3(256, 1, 1), 0, stream>>>(x, sigma, out);
}